// Round 1
// baseline (1075.795 us; speedup 1.0000x reference)
//
#include <hip/hip_runtime.h>
#include <hip/hip_bf16.h>
#include <math.h>

// Problem constants (fixed by reference)
constexpr int NB  = 8;     // batches
constexpr int NN  = 512;   // proposals per batch
constexpr int NC  = 256;   // channels C
constexpr int NCQ = 64;    // CQ = C/4
constexpr int NHW = 49;    // P*P
constexpr int HWP = 52;    // padded hw stride (13 float4)
constexpr int NM  = NB * NN; // 4096

// Workspace layout (float offsets)
constexpr size_t WS_SMEAN = 0;                               // 8*256
constexpr size_t WS_YS    = 2048;                            // 8*256*52
constexpr size_t WS_US    = WS_YS + (size_t)NB * NC * HWP;   // 108544
constexpr size_t WS_QMEAN = WS_US + (size_t)NB * NCQ * HWP;  // 135168
constexpr size_t WS_SP    = WS_QMEAN + (size_t)NM * NC;      // 1183744

// Output layout (floats): boxes[4096*4] | scores[4096] | keep[4096]
constexpr size_t OUT_SCORES = (size_t)NM * 4;  // 16384
constexpr size_t OUT_KEEP   = OUT_SCORES + NM; // 20480

__device__ __forceinline__ float block_reduce_sum(float v, float* red) {
    int t = threadIdx.x;
#pragma unroll
    for (int off = 32; off > 0; off >>= 1) v += __shfl_down(v, off, 64);
    __syncthreads();               // protect red from previous use
    if ((t & 63) == 0) red[t >> 6] = v;
    __syncthreads();
    return red[0] + red[1] + red[2] + red[3];
}

// ---------------------------------------------------------------------------
// K1: per-batch precompute. grid = 32 (b*4 + o-quarter), block = 256.
//   s_mean[b,c], y_s[b,o,hw] = (Wcor @ x_s)[o,hw], u_s[b,o,hw] = (W1[:,256:] @ x_s)
// ---------------------------------------------------------------------------
__global__ __launch_bounds__(256) void k_prep_s(
    const float* __restrict__ bfs, const float* __restrict__ Wcor,
    const float* __restrict__ W1, float* __restrict__ ws)
{
    __shared__ __align__(16) float s_xs[NC * HWP];
    int t = threadIdx.x;
    int b = blockIdx.x >> 2;
    int oq = blockIdx.x & 3;

    for (int i = t; i < NC * 3; i += 256) {
        int c = i / 3;
        s_xs[c * HWP + NHW + (i - c * 3)] = 0.f;
    }
    const float* g = bfs + (size_t)b * (NC * NHW);
    for (int i = t; i < NC * NHW; i += 256) {
        int c = i / NHW; int hw = i - c * NHW;
        s_xs[c * HWP + hw] = g[i];
    }
    __syncthreads();

    if (oq == 0) {  // s_mean
        const float* r = s_xs + t * HWP;
        float s = 0.f;
#pragma unroll
        for (int hw = 0; hw < NHW; ++hw) s += r[hw];
        ws[WS_SMEAN + (size_t)b * NC + t] = s / 49.0f;
    }

    // y_s for o in [oq*64, oq*64+64)
    {
        int o = oq * 64 + (t & 63);
        int part = t >> 6;
        const float4* wrow = (const float4*)(Wcor + o * NC);
        float* dst = ws + WS_YS + ((size_t)b * NC + o) * HWP;
        if (part < 3) {
            int hw0 = part * 16;
            float a[16];
#pragma unroll
            for (int j = 0; j < 16; ++j) a[j] = 0.f;
            for (int c4 = 0; c4 < NC / 4; ++c4) {
                float4 w4 = wrow[c4];
                const float* wc = (const float*)&w4;
#pragma unroll
                for (int sub = 0; sub < 4; ++sub) {
                    float w = wc[sub];
                    const float4* xr = (const float4*)(s_xs + (c4 * 4 + sub) * HWP + hw0);
#pragma unroll
                    for (int j4 = 0; j4 < 4; ++j4) {
                        float4 x = xr[j4];
                        a[4*j4+0] = fmaf(w, x.x, a[4*j4+0]);
                        a[4*j4+1] = fmaf(w, x.y, a[4*j4+1]);
                        a[4*j4+2] = fmaf(w, x.z, a[4*j4+2]);
                        a[4*j4+3] = fmaf(w, x.w, a[4*j4+3]);
                    }
                }
            }
#pragma unroll
            for (int j = 0; j < 16; ++j) dst[hw0 + j] = a[j];
        } else {
            const float* wr = Wcor + o * NC;
            float a0 = 0.f;
            for (int c = 0; c < NC; ++c) a0 = fmaf(wr[c], s_xs[c * HWP + 48], a0);
            dst[48] = a0; dst[49] = 0.f; dst[50] = 0.f; dst[51] = 0.f;
        }
    }

    if (oq == 0) {  // u_s (64 output channels)
        int o2 = t & 63;
        int part = t >> 6;
        const float* wbase = W1 + o2 * (2 * NC) + NC;
        float* dst = ws + WS_US + ((size_t)b * NCQ + o2) * HWP;
        if (part < 3) {
            int hw0 = part * 16;
            float a[16];
#pragma unroll
            for (int j = 0; j < 16; ++j) a[j] = 0.f;
            const float4* wrow = (const float4*)wbase;
            for (int c4 = 0; c4 < NC / 4; ++c4) {
                float4 w4 = wrow[c4];
                const float* wc = (const float*)&w4;
#pragma unroll
                for (int sub = 0; sub < 4; ++sub) {
                    float w = wc[sub];
                    const float4* xr = (const float4*)(s_xs + (c4 * 4 + sub) * HWP + hw0);
#pragma unroll
                    for (int j4 = 0; j4 < 4; ++j4) {
                        float4 x = xr[j4];
                        a[4*j4+0] = fmaf(w, x.x, a[4*j4+0]);
                        a[4*j4+1] = fmaf(w, x.y, a[4*j4+1]);
                        a[4*j4+2] = fmaf(w, x.z, a[4*j4+2]);
                        a[4*j4+3] = fmaf(w, x.w, a[4*j4+3]);
                    }
                }
            }
#pragma unroll
            for (int j = 0; j < 16; ++j) dst[hw0 + j] = a[j];
        } else {
            float a0 = 0.f;
            for (int c = 0; c < NC; ++c) a0 = fmaf(wbase[c], s_xs[c * HWP + 48], a0);
            dst[48] = a0;
        }
    }
}

// ---------------------------------------------------------------------------
// K2: heavy per-m kernel. grid = 4096, block = 256.
//   q_mean, correlation->score_cor, x1(relu W1q x_q + u_s), pool, conv W2,
//   W3, pool, score_pr + deltas -> decode boxes -> d_out, score_partial -> ws
// ---------------------------------------------------------------------------
__global__ __launch_bounds__(256, 2) void k_heavy(
    const float* __restrict__ bfq, const float* __restrict__ Wcor,
    const float* __restrict__ W1, const float* __restrict__ W2,
    const float* __restrict__ W3,
    const float* __restrict__ scor_w, const float* __restrict__ scor_b,
    const float* __restrict__ spr_w, const float* __restrict__ spr_b,
    const float* __restrict__ dpr_w, const float* __restrict__ dpr_b,
    const float* __restrict__ proposals, const int* __restrict__ image_size,
    float* __restrict__ ws, float* __restrict__ out)
{
    __shared__ __align__(16) float s_xq[NC * HWP];   // 53248 B (reused later)
    __shared__ __align__(16) float s_x1[NCQ * HWP];  // 13312 B
    __shared__ float s_red[8];

    int t = threadIdx.x;
    int m = blockIdx.x;
    int b = m >> 9;

    for (int i = t; i < NC * 3; i += 256) {
        int c = i / 3;
        s_xq[c * HWP + NHW + (i - c * 3)] = 0.f;
    }
    const float* g = bfq + (size_t)m * (NC * NHW);
    for (int i = t; i < NC * NHW; i += 256) {
        int c = i / NHW; int hw = i - c * NHW;
        s_xq[c * HWP + hw] = g[i];
    }
    __syncthreads();

    // q_mean
    {
        const float* r = s_xq + t * HWP;
        float s = 0.f;
#pragma unroll
        for (int hw = 0; hw < NHW; ++hw) s += r[hw];
        ws[WS_QMEAN + (size_t)m * NC + t] = s / 49.0f;
    }

    // correlation: z[o,:] = Wcor[o,:] @ x_q ; corr = <z, y_s[b,o,:]> ; relu ; *scor_w
    float r_cor;
    {
        float a[52];
#pragma unroll
        for (int j = 0; j < 52; ++j) a[j] = 0.f;
        const int o = t;
        const float4* wrow = (const float4*)(Wcor + o * NC);
        for (int c4 = 0; c4 < NC / 4; ++c4) {
            float4 w4 = wrow[c4];
            const float* wc = (const float*)&w4;
#pragma unroll
            for (int sub = 0; sub < 4; ++sub) {
                float w = wc[sub];
                const float4* xr = (const float4*)(s_xq + (c4 * 4 + sub) * HWP);
#pragma unroll
                for (int j = 0; j < 13; ++j) {
                    float4 x = xr[j];
                    a[4*j+0] = fmaf(w, x.x, a[4*j+0]);
                    a[4*j+1] = fmaf(w, x.y, a[4*j+1]);
                    a[4*j+2] = fmaf(w, x.z, a[4*j+2]);
                    a[4*j+3] = fmaf(w, x.w, a[4*j+3]);
                }
            }
        }
        const float4* ys = (const float4*)(ws + WS_YS + ((size_t)b * NC + o) * HWP);
        float corr = 0.f;
#pragma unroll
        for (int j = 0; j < 13; ++j) {
            float4 y = ys[j];
            corr += a[4*j+0]*y.x + a[4*j+1]*y.y + a[4*j+2]*y.z + a[4*j+3]*y.w;
        }
        r_cor = block_reduce_sum(fmaxf(corr, 0.f) * scor_w[o], s_red);
    }

    // x1 = relu(W1[:, :256] @ x_q + u_s)  -> s_x1 (64 x 49)
    {
        int o2 = t & 63;
        int part = t >> 6;
        const float* wr0 = W1 + o2 * (2 * NC);
        if (part < 3) {
            int hw0 = part * 16;
            float a[16];
#pragma unroll
            for (int j = 0; j < 16; ++j) a[j] = 0.f;
            const float4* wrow = (const float4*)wr0;
            for (int c4 = 0; c4 < NC / 4; ++c4) {
                float4 w4 = wrow[c4];
                const float* wc = (const float*)&w4;
#pragma unroll
                for (int sub = 0; sub < 4; ++sub) {
                    float w = wc[sub];
                    const float4* xr = (const float4*)(s_xq + (c4 * 4 + sub) * HWP + hw0);
#pragma unroll
                    for (int j4 = 0; j4 < 4; ++j4) {
                        float4 x = xr[j4];
                        a[4*j4+0] = fmaf(w, x.x, a[4*j4+0]);
                        a[4*j4+1] = fmaf(w, x.y, a[4*j4+1]);
                        a[4*j4+2] = fmaf(w, x.z, a[4*j4+2]);
                        a[4*j4+3] = fmaf(w, x.w, a[4*j4+3]);
                    }
                }
            }
            const float* us = ws + WS_US + ((size_t)b * NCQ + o2) * HWP + hw0;
#pragma unroll
            for (int j = 0; j < 16; ++j)
                s_x1[o2 * HWP + hw0 + j] = fmaxf(a[j] + us[j], 0.f);
        } else {
            float a0 = 0.f;
            for (int c = 0; c < NC; ++c) a0 = fmaf(wr0[c], s_xq[c * HWP + 48], a0);
            s_x1[o2 * HWP + 48] =
                fmaxf(a0 + ws[WS_US + ((size_t)b * NCQ + o2) * HWP + 48], 0.f);
        }
    }
    __syncthreads();   // xq reads done; x1 complete. Reuse s_xq below.

    // avgpool3 7x7 -> 5x5 : p1 (64 x 25) in s_xq[0..1599]
    float* s_p1 = s_xq;
    for (int i = t; i < NCQ * 25; i += 256) {
        int ch = i / 25; int pos = i - ch * 25;
        int py = pos / 5; int px = pos - py * 5;
        const float* base = s_x1 + ch * HWP + py * 7 + px;
        float s = base[0] + base[1] + base[2]
                + base[7] + base[8] + base[9]
                + base[14] + base[15] + base[16];
        s_p1[ch * 25 + pos] = s / 9.0f;
    }
    __syncthreads();

    // conv3x3 VALID (64->64): c2 (64 x 9, stride 12) in s_xq[1600..2367]
    float* s_c2 = s_xq + 1600;
    for (int i = t; i < NCQ * 9; i += 256) {
        int oc = i / 9; int pos = i - oc * 9;
        int py = pos / 3; int px = pos - py * 3;
        const float* wb = W2 + (size_t)oc * (NCQ * 9);
        float acc = 0.f;
        for (int ic = 0; ic < NCQ; ++ic) {
            const float* pb = s_p1 + ic * 25 + py * 5 + px;
            const float* wi = wb + ic * 9;
            acc = fmaf(pb[0],  wi[0], acc);
            acc = fmaf(pb[1],  wi[1], acc);
            acc = fmaf(pb[2],  wi[2], acc);
            acc = fmaf(pb[5],  wi[3], acc);
            acc = fmaf(pb[6],  wi[4], acc);
            acc = fmaf(pb[7],  wi[5], acc);
            acc = fmaf(pb[10], wi[6], acc);
            acc = fmaf(pb[11], wi[7], acc);
            acc = fmaf(pb[12], wi[8], acc);
        }
        s_c2[oc * 12 + pos] = fmaxf(acc, 0.f);
    }
    __syncthreads();

    // W3 (256x64) + relu + avgpool3 3x3->1x1
    float xfin;
    {
        int o = t;
        float xw[9];
#pragma unroll
        for (int p2 = 0; p2 < 9; ++p2) xw[p2] = 0.f;
        const float* wr = W3 + o * NCQ;
        for (int ic = 0; ic < NCQ; ++ic) {
            float w = wr[ic];
            const float* cb = s_c2 + ic * 12;
#pragma unroll
            for (int p2 = 0; p2 < 9; ++p2) xw[p2] = fmaf(w, cb[p2], xw[p2]);
        }
        float s = 0.f;
#pragma unroll
        for (int p2 = 0; p2 < 9; ++p2) s += fmaxf(xw[p2], 0.f);
        xfin = s / 9.0f;
    }

    float r_pr = block_reduce_sum(xfin * spr_w[t], s_red);
    float r_d0 = block_reduce_sum(xfin * dpr_w[0 * NC + t], s_red);
    float r_d1 = block_reduce_sum(xfin * dpr_w[1 * NC + t], s_red);
    float r_d2 = block_reduce_sum(xfin * dpr_w[2 * NC + t], s_red);
    float r_d3 = block_reduce_sum(xfin * dpr_w[3 * NC + t], s_red);

    if (t == 0) {
        float score_pr  = r_pr + spr_b[0];
        float score_cor = r_cor + scor_b[0];
        ws[WS_SP + m] = score_pr + score_cor;

        float d0 = r_d0 + dpr_b[0];
        float d1 = r_d1 + dpr_b[1];
        float d2 = fminf(r_d2 + dpr_b[2], 4.135166556742356f);
        float d3 = fminf(r_d3 + dpr_b[3], 4.135166556742356f);

        const float* pr = proposals + (size_t)m * 4;
        float x1p = pr[0], y1p = pr[1], x2p = pr[2], y2p = pr[3];
        float w  = x2p - x1p, h = y2p - y1p;
        float cx = x1p + 0.5f * w, cy = y1p + 0.5f * h;
        float pcx = d0 * w + cx, pcy = d1 * h + cy;
        float pw = expf(d2) * w, ph = expf(d3) * h;
        float Wf = (float)image_size[1];
        float Hf = (float)image_size[0];
        out[(size_t)m * 4 + 0] = fminf(fmaxf(pcx - 0.5f * pw, 0.f), Wf);
        out[(size_t)m * 4 + 1] = fminf(fmaxf(pcy - 0.5f * ph, 0.f), Hf);
        out[(size_t)m * 4 + 2] = fminf(fmaxf(pcx + 0.5f * pw, 0.f), Wf);
        out[(size_t)m * 4 + 3] = fminf(fmaxf(pcy + 0.5f * ph, 0.f), Hf);
    }
}

// ---------------------------------------------------------------------------
// K3: FC path, 8 m's per block. grid = 512, block = 256.
// ---------------------------------------------------------------------------
__global__ __launch_bounds__(256) void k_fc(
    const float* __restrict__ fc1_w, const float* __restrict__ fc1_b,
    const float* __restrict__ fc2_w, const float* __restrict__ fc2_b,
    const float* __restrict__ sfc_w, const float* __restrict__ sfc_b,
    float* __restrict__ ws, float* __restrict__ out)
{
    __shared__ __align__(16) float sxfc[8][2 * NC];
    __shared__ __align__(16) float sh1[8][NC];
    __shared__ float s_red[8];
    int t = threadIdx.x;
    int m0 = blockIdx.x * 8;

#pragma unroll
    for (int mi = 0; mi < 8; ++mi) {
        int mg = m0 + mi;
        int b = mg >> 9;
        sxfc[mi][t]      = ws[WS_QMEAN + (size_t)mg * NC + t];
        sxfc[mi][NC + t] = ws[WS_SMEAN + (size_t)b * NC + t];
    }
    __syncthreads();

    {
        const float4* wr = (const float4*)(fc1_w + t * (2 * NC));
        float acc[8];
#pragma unroll
        for (int mi = 0; mi < 8; ++mi) acc[mi] = 0.f;
        for (int k4 = 0; k4 < (2 * NC) / 4; ++k4) {
            float4 w = wr[k4];
#pragma unroll
            for (int mi = 0; mi < 8; ++mi) {
                float4 x = ((const float4*)sxfc[mi])[k4];
                acc[mi] = fmaf(w.x, x.x, acc[mi]);
                acc[mi] = fmaf(w.y, x.y, acc[mi]);
                acc[mi] = fmaf(w.z, x.z, acc[mi]);
                acc[mi] = fmaf(w.w, x.w, acc[mi]);
            }
        }
        float bb = fc1_b[t];
#pragma unroll
        for (int mi = 0; mi < 8; ++mi) sh1[mi][t] = fmaxf(acc[mi] + bb, 0.f);
    }
    __syncthreads();

    float val[8];
    {
        const float4* wr = (const float4*)(fc2_w + t * NC);
        float acc[8];
#pragma unroll
        for (int mi = 0; mi < 8; ++mi) acc[mi] = 0.f;
        for (int k4 = 0; k4 < NC / 4; ++k4) {
            float4 w = wr[k4];
#pragma unroll
            for (int mi = 0; mi < 8; ++mi) {
                float4 x = ((const float4*)sh1[mi])[k4];
                acc[mi] = fmaf(w.x, x.x, acc[mi]);
                acc[mi] = fmaf(w.y, x.y, acc[mi]);
                acc[mi] = fmaf(w.z, x.z, acc[mi]);
                acc[mi] = fmaf(w.w, x.w, acc[mi]);
            }
        }
        float bb = fc2_b[t];
        float sw = sfc_w[t];
#pragma unroll
        for (int mi = 0; mi < 8; ++mi)
            val[mi] = sw * fmaxf(acc[mi] + bb, 0.f);
    }

#pragma unroll
    for (int mi = 0; mi < 8; ++mi) {
        float r = block_reduce_sum(val[mi], s_red);
        if (t == 0) {
            float tot = ws[WS_SP + m0 + mi] + (r + sfc_b[0]);
            out[OUT_SCORES + m0 + mi] = 1.0f / (1.0f + expf(-tot));
        }
    }
}

// ---------------------------------------------------------------------------
// K4: per-batch NMS. grid = 8, block = 256.
// ---------------------------------------------------------------------------
__global__ __launch_bounds__(256) void k_nms(float* __restrict__ out)
{
    __shared__ float ssc[NN];
    __shared__ float sx1[NN], sy1[NN], sx2[NN], sy2[NN], sar[NN];
    __shared__ int sidx[NN], skeep[NN];
    int t = threadIdx.x;
    int b = blockIdx.x;
    const float* sc_g = out + OUT_SCORES + (size_t)b * NN;
    const float* bx_g = out + (size_t)b * NN * 4;

    for (int i = t; i < NN; i += 256) ssc[i] = sc_g[i];
    __syncthreads();

    // stable descending rank (unique) -> scatter into sorted arrays
    for (int i = t; i < NN; i += 256) {
        float si = ssc[i];
        int r = 0;
        for (int j = 0; j < NN; ++j) {
            float sj = ssc[j];
            r += (int)((sj > si) || (sj == si && j < i));
        }
        float x1 = bx_g[i * 4 + 0], y1 = bx_g[i * 4 + 1];
        float x2 = bx_g[i * 4 + 2], y2 = bx_g[i * 4 + 3];
        sx1[r] = x1; sy1[r] = y1; sx2[r] = x2; sy2[r] = y2;
        sar[r] = fmaxf(x2 - x1, 0.f) * fmaxf(y2 - y1, 0.f);
        sidx[r] = i;
        skeep[r] = 1;
    }
    __syncthreads();

    for (int i = 0; i < NN - 1; ++i) {
        int ki = skeep[i];
        float xi1 = sx1[i], yi1 = sy1[i], xi2 = sx2[i], yi2 = sy2[i], ai = sar[i];
        if (ki) {
            for (int r = t; r < NN; r += 256) {
                if (r > i && skeep[r]) {
                    float xx1 = fmaxf(xi1, sx1[r]);
                    float yy1 = fmaxf(yi1, sy1[r]);
                    float xx2 = fminf(xi2, sx2[r]);
                    float yy2 = fminf(yi2, sy2[r]);
                    float inter = fmaxf(xx2 - xx1, 0.f) * fmaxf(yy2 - yy1, 0.f);
                    float iou = inter / fmaxf(ai + sar[r] - inter, 1e-9f);
                    if (iou > 0.5f) skeep[r] = 0;
                }
            }
        }
        __syncthreads();
    }

    for (int r = t; r < NN; r += 256)
        out[OUT_KEEP + (size_t)b * NN + sidx[r]] = skeep[r] ? 1.0f : 0.0f;
}

// ---------------------------------------------------------------------------
extern "C" void kernel_launch(void* const* d_in, const int* in_sizes, int n_in,
                              void* d_out, int out_size, void* d_ws, size_t ws_size,
                              hipStream_t stream) {
    const float* bfq       = (const float*)d_in[0];
    const float* bfs       = (const float*)d_in[1];
    const float* proposals = (const float*)d_in[2];
    const int*   image_sz  = (const int*)d_in[3];
    const float* W1        = (const float*)d_in[4];
    const float* W2        = (const float*)d_in[5];
    const float* W3        = (const float*)d_in[6];
    const float* Wcor      = (const float*)d_in[7];
    const float* fc1_w     = (const float*)d_in[8];
    const float* fc1_b     = (const float*)d_in[9];
    const float* fc2_w     = (const float*)d_in[10];
    const float* fc2_b     = (const float*)d_in[11];
    const float* sfc_w     = (const float*)d_in[12];
    const float* sfc_b     = (const float*)d_in[13];
    const float* scor_w    = (const float*)d_in[14];
    const float* scor_b    = (const float*)d_in[15];
    const float* spr_w     = (const float*)d_in[16];
    const float* spr_b     = (const float*)d_in[17];
    const float* dpr_w     = (const float*)d_in[18];
    const float* dpr_b     = (const float*)d_in[19];
    float* out = (float*)d_out;
    float* ws  = (float*)d_ws;

    k_prep_s<<<32, 256, 0, stream>>>(bfs, Wcor, W1, ws);
    k_heavy<<<NM, 256, 0, stream>>>(bfq, Wcor, W1, W2, W3,
                                    scor_w, scor_b, spr_w, spr_b,
                                    dpr_w, dpr_b, proposals, image_sz, ws, out);
    k_fc<<<NM / 8, 256, 0, stream>>>(fc1_w, fc1_b, fc2_w, fc2_b,
                                     sfc_w, sfc_b, ws, out);
    k_nms<<<NB, 256, 0, stream>>>(out);
}